// Round 1
// baseline (1340.409 us; speedup 1.0000x reference)
//
#include <hip/hip_runtime.h>
#include <hip/hip_fp16.h>

typedef _Float16 h2 __attribute__((ext_vector_type(2)));
typedef unsigned int u32;

#define B_ 256
#define T_ 512
#define F_ 256
#define H_ 512

#define LDSP 72   /* weight pairs (rows/2) resident in LDS  */
#define REGP 184  /* weight pairs resident in VGPRs         */

__device__ __forceinline__ float dot2f(u32 a, u32 b, float c) {
#if __has_builtin(__builtin_amdgcn_fdot2)
    return __builtin_amdgcn_fdot2(__builtin_bit_cast(h2, a), __builtin_bit_cast(h2, b), c, false);
#else
    h2 x = __builtin_bit_cast(h2, a), y = __builtin_bit_cast(h2, b);
    return c + (float)x[0] * (float)y[0] + (float)x[1] * (float)y[1];
#endif
}

__device__ __forceinline__ u32 packh2(float a, float b) {
    h2 v; v[0] = (_Float16)a; v[1] = (_Float16)b;
    return __builtin_bit_cast(u32, v);
}

// Pack Wx (128 pair-rows x 512) and Wh (256 pair-rows x 512) into f16x2.
__global__ void prepack_kernel(const float* __restrict__ Wx, const float* __restrict__ Wh,
                               u32* __restrict__ Wxpk, u32* __restrict__ Whpk) {
    int i = blockIdx.x * 256 + threadIdx.x;
    if (i < 128 * 512) {
        int p = i >> 9, j = i & 511;
        Wxpk[i] = packh2(Wx[(2 * p) * H_ + j], Wx[(2 * p + 1) * H_ + j]);
    }
    int k = i - 128 * 512;
    if (k >= 0 && k < 256 * 512) {
        int p = k >> 9, j = k & 511;
        Whpk[k] = packh2(Wh[(2 * p) * H_ + j], Wh[(2 * p + 1) * H_ + j]);
    }
}

// xp[row][j] = f16( sum_f x[row][f] * Wx[f][j] + b[j] ), rows = B*T, 16 rows/block.
__global__ __launch_bounds__(512) void xp_gemm_kernel(const float* __restrict__ x,
                                                      const u32* __restrict__ Wxpk,
                                                      const float* __restrict__ b,
                                                      __half* __restrict__ xp) {
    __shared__ u32 ldsx[16 * 128];  // layout [p][r]: pair p of row r
    const int j = threadIdx.x;
    const long row0 = (long)blockIdx.x * 16;
    const float2* x2 = (const float2*)(x + row0 * F_);  // 16 rows * 128 float2
    for (int i = j; i < 16 * 128; i += 512) {
        int p = i >> 4, r = i & 15;
        float2 v = x2[r * 128 + p];
        ldsx[i] = packh2(v.x, v.y);
    }
    __syncthreads();
    const uint4* lx4 = (const uint4*)ldsx;
    float acc[16];
#pragma unroll
    for (int r = 0; r < 16; ++r) acc[r] = 0.f;
    for (int p = 0; p < 128; ++p) {
        u32 w = Wxpk[p * 512 + j];
        uint4 a0 = lx4[p * 4 + 0], a1 = lx4[p * 4 + 1], a2 = lx4[p * 4 + 2], a3 = lx4[p * 4 + 3];
        u32 hv[16] = {a0.x, a0.y, a0.z, a0.w, a1.x, a1.y, a1.z, a1.w,
                      a2.x, a2.y, a2.z, a2.w, a3.x, a3.y, a3.z, a3.w};
#pragma unroll
        for (int r = 0; r < 16; ++r) acc[r] = dot2f(hv[r], w, acc[r]);
    }
    float bj = b[j];
#pragma unroll
    for (int r = 0; r < 16; ++r)
        xp[(row0 + r) * H_ + j] = __float2half(acc[r] + bj);
}

// Persistent per-batch-row recurrence. 256 blocks x 512 threads, Wh f16 resident
// in LDS (72 pairs) + VGPRs (184 pairs/thread, one column per thread).
__global__ __launch_bounds__(512, 2) void rnn_kernel(const __half* __restrict__ xp,
                                                     const u32* __restrict__ Whpk,
                                                     const float* __restrict__ Wfc,
                                                     const float* __restrict__ bfc,
                                                     float* __restrict__ out) {
    extern __shared__ u32 lds[];
    // w2[q*512 + j] = {pair 2q, pair 2q+1} for column j; q in [0,36) -> pairs 0..71
    uint2* w2 = (uint2*)lds;                     // 36*512*8 = 147456 B
    __half* hb = (__half*)(lds + 36 * 512 * 2);  // 2 x 512 halfs (double buffer), 2048 B
    const int j = threadIdx.x;
    const int b = blockIdx.x;

    for (int q = 0; q < 36; ++q) {
        uint2 v;
        v.x = Whpk[(2 * q) * 512 + j];
        v.y = Whpk[(2 * q + 1) * 512 + j];
        w2[q * 512 + j] = v;
    }
    u32 wreg[REGP];
#pragma unroll
    for (int i = 0; i < REGP; ++i) wreg[i] = Whpk[(LDSP + i) * 512 + j];

    hb[j] = __float2half(0.f);
    hb[512 + j] = __float2half(0.f);
    const __half* xprow = xp + (size_t)b * T_ * H_ + j;
    float hn = 0.f;
    float xpv;
    __syncthreads();
    xpv = __half2float(xprow[0]);

    int cur = 0;
    for (int t = 0; t < T_; ++t) {
        float acc = xpv;
        int tn = (t + 1 < T_) ? (t + 1) : (T_ - 1);
        __half nxt = xprow[(size_t)tn * H_];  // prefetch next step's xp
        const uint4* h4 = (const uint4*)(hb + cur * 512);
        // LDS-resident pairs 0..71 (chunks of 8 pairs)
#pragma unroll
        for (int c = 0; c < 9; ++c) {
            uint4 ha = h4[2 * c], hc = h4[2 * c + 1];
            uint2 w0 = w2[(4 * c + 0) * 512 + j];
            uint2 w1 = w2[(4 * c + 1) * 512 + j];
            uint2 wv2 = w2[(4 * c + 2) * 512 + j];
            uint2 w3 = w2[(4 * c + 3) * 512 + j];
            acc = dot2f(ha.x, w0.x, acc);
            acc = dot2f(ha.y, w0.y, acc);
            acc = dot2f(ha.z, w1.x, acc);
            acc = dot2f(ha.w, w1.y, acc);
            acc = dot2f(hc.x, wv2.x, acc);
            acc = dot2f(hc.y, wv2.y, acc);
            acc = dot2f(hc.z, w3.x, acc);
            acc = dot2f(hc.w, w3.y, acc);
        }
        // register-resident pairs 72..255
#pragma unroll
        for (int c = 0; c < 23; ++c) {
            uint4 ha = h4[18 + 2 * c], hc = h4[19 + 2 * c];
            acc = dot2f(ha.x, wreg[8 * c + 0], acc);
            acc = dot2f(ha.y, wreg[8 * c + 1], acc);
            acc = dot2f(ha.z, wreg[8 * c + 2], acc);
            acc = dot2f(ha.w, wreg[8 * c + 3], acc);
            acc = dot2f(hc.x, wreg[8 * c + 4], acc);
            acc = dot2f(hc.y, wreg[8 * c + 5], acc);
            acc = dot2f(hc.z, wreg[8 * c + 6], acc);
            acc = dot2f(hc.w, wreg[8 * c + 7], acc);
        }
        hn = tanhf(acc);
        hb[(cur ^ 1) * 512 + j] = __float2half(hn);
        xpv = __half2float(nxt);
        __syncthreads();
        cur ^= 1;
    }

    // epilogue: out[b] = h_last . Wfc + bfc - 0.05
    float v = hn * Wfc[j];
#pragma unroll
    for (int off = 32; off; off >>= 1) v += __shfl_down(v, off, 64);
    float* red = (float*)hb;  // reuse LDS (all reads of hb are done)
    int lane = j & 63, wid = j >> 6;
    if (lane == 0) red[wid] = v;
    __syncthreads();
    if (j == 0) {
        float s = 0.f;
        for (int w = 0; w < 8; ++w) s += red[w];
        out[b] = s + bfc[0] - 0.05f;
    }
}

extern "C" void kernel_launch(void* const* d_in, const int* in_sizes, int n_in,
                              void* d_out, int out_size, void* d_ws, size_t ws_size,
                              hipStream_t stream) {
    const float* x   = (const float*)d_in[0];
    const float* Wx  = (const float*)d_in[1];
    const float* Wh  = (const float*)d_in[2];
    const float* b   = (const float*)d_in[3];
    const float* Wfc = (const float*)d_in[4];
    const float* bfc = (const float*)d_in[5];
    float* out = (float*)d_out;

    char* ws = (char*)d_ws;
    __half* xp = (__half*)ws;                               // 134,217,728 B
    u32* Wxpk  = (u32*)(ws + 134217728);                    //     262,144 B
    u32* Whpk  = (u32*)(ws + 134217728 + 262144);           //     524,288 B

    prepack_kernel<<<768, 256, 0, stream>>>(Wx, Wh, Wxpk, Whpk);
    xp_gemm_kernel<<<(B_ * T_) / 16, 512, 0, stream>>>(x, Wxpk, b, xp);

    const int dyn = 36 * 512 * 8 + 2048;  // 149504 B
    (void)hipFuncSetAttribute((const void*)rnn_kernel,
                              hipFuncAttributeMaxDynamicSharedMemorySize, dyn);
    rnn_kernel<<<B_, 512, dyn, stream>>>(xp, Whpk, Wfc, bfc, out);
}

// Round 2
// 1328.853 us; speedup vs baseline: 1.0087x; 1.0087x over previous
//
#include <hip/hip_runtime.h>
#include <hip/hip_fp16.h>

typedef _Float16 h2 __attribute__((ext_vector_type(2)));
typedef unsigned int u32;

#define B_ 256
#define T_ 512
#define F_ 256
#define H_ 512

#define LDSP 64   /* weight pairs (rows/2) resident in LDS  */
#define REGP 192  /* weight pairs resident in VGPRs         */

__device__ __forceinline__ float dot2f(u32 a, u32 b, float c) {
#if __has_builtin(__builtin_amdgcn_fdot2)
    return __builtin_amdgcn_fdot2(__builtin_bit_cast(h2, a), __builtin_bit_cast(h2, b), c, false);
#else
    h2 x = __builtin_bit_cast(h2, a), y = __builtin_bit_cast(h2, b);
    return c + (float)x[0] * (float)y[0] + (float)x[1] * (float)y[1];
#endif
}

__device__ __forceinline__ u32 packh2(float a, float b) {
    h2 v; v[0] = (_Float16)a; v[1] = (_Float16)b;
    return __builtin_bit_cast(u32, v);
}

// Pack Wx (128 pair-rows x 512) and Wh (256 pair-rows x 512) into f16x2.
__global__ void prepack_kernel(const float* __restrict__ Wx, const float* __restrict__ Wh,
                               u32* __restrict__ Wxpk, u32* __restrict__ Whpk) {
    int i = blockIdx.x * 256 + threadIdx.x;
    if (i < 128 * 512) {
        int p = i >> 9, j = i & 511;
        Wxpk[i] = packh2(Wx[(2 * p) * H_ + j], Wx[(2 * p + 1) * H_ + j]);
    }
    int k = i - 128 * 512;
    if (k >= 0 && k < 256 * 512) {
        int p = k >> 9, j = k & 511;
        Whpk[k] = packh2(Wh[(2 * p) * H_ + j], Wh[(2 * p + 1) * H_ + j]);
    }
}

// xp[row][j] = f16( sum_f x[row][f] * Wx[f][j] + b[j] ), rows = B*T, 16 rows/block.
__global__ __launch_bounds__(512) void xp_gemm_kernel(const float* __restrict__ x,
                                                      const u32* __restrict__ Wxpk,
                                                      const float* __restrict__ b,
                                                      __half* __restrict__ xp) {
    __shared__ u32 ldsx[16 * 128];  // layout [p][r]: pair p of row r
    const int j = threadIdx.x;
    const long row0 = (long)blockIdx.x * 16;
    const float2* x2 = (const float2*)(x + row0 * F_);  // 16 rows * 128 float2
    for (int i = j; i < 16 * 128; i += 512) {
        int p = i >> 4, r = i & 15;
        float2 v = x2[r * 128 + p];
        ldsx[i] = packh2(v.x, v.y);
    }
    __syncthreads();
    const uint4* lx4 = (const uint4*)ldsx;
    float acc[16];
#pragma unroll
    for (int r = 0; r < 16; ++r) acc[r] = 0.f;
    for (int p = 0; p < 128; ++p) {
        u32 w = Wxpk[p * 512 + j];
        uint4 a0 = lx4[p * 4 + 0], a1 = lx4[p * 4 + 1], a2 = lx4[p * 4 + 2], a3 = lx4[p * 4 + 3];
        u32 hv[16] = {a0.x, a0.y, a0.z, a0.w, a1.x, a1.y, a1.z, a1.w,
                      a2.x, a2.y, a2.z, a2.w, a3.x, a3.y, a3.z, a3.w};
#pragma unroll
        for (int r = 0; r < 16; ++r) acc[r] = dot2f(hv[r], w, acc[r]);
    }
    float bj = b[j];
#pragma unroll
    for (int r = 0; r < 16; ++r)
        xp[(row0 + r) * H_ + j] = __float2half(acc[r] + bj);
}

// Persistent per-batch-row recurrence. 256 blocks x 512 threads, Wh f16 resident
// in LDS (64 pairs) + VGPRs (192 pairs/thread, one column per thread).
// __launch_bounds__(512, 1): with 512-thread blocks the launchability cap is
// 256 VGPR/wave (full file at 8 waves/CU) -> no spill for wreg[192]+~40 live.
__global__ __launch_bounds__(512, 1) void rnn_kernel(const __half* __restrict__ xp,
                                                     const u32* __restrict__ Whpk,
                                                     const float* __restrict__ Wfc,
                                                     const float* __restrict__ bfc,
                                                     float* __restrict__ out) {
    extern __shared__ u32 lds[];
    // w2[q*512 + j] = {pair 2q, pair 2q+1} for column j; q in [0,32) -> pairs 0..63
    uint2* w2 = (uint2*)lds;                     // 32*512*8 = 131072 B
    __half* hb = (__half*)(lds + 32 * 512 * 2);  // 2 x 512 halfs (double buffer), 2048 B
    const int j = threadIdx.x;
    const int b = blockIdx.x;

    for (int q = 0; q < 32; ++q) {
        uint2 v;
        v.x = Whpk[(2 * q) * 512 + j];
        v.y = Whpk[(2 * q + 1) * 512 + j];
        w2[q * 512 + j] = v;
    }
    u32 wreg[REGP];
#pragma unroll
    for (int i = 0; i < REGP; ++i) wreg[i] = Whpk[(LDSP + i) * 512 + j];

    hb[j] = __float2half(0.f);
    hb[512 + j] = __float2half(0.f);
    const __half* xprow = xp + (size_t)b * T_ * H_ + j;
    float hn = 0.f;
    float xpv;
    __syncthreads();
    xpv = __half2float(xprow[0]);

    int cur = 0;
    for (int t = 0; t < T_; ++t) {
        float acc = xpv;
        int tn = (t + 1 < T_) ? (t + 1) : (T_ - 1);
        __half nxt = xprow[(size_t)tn * H_];  // prefetch next step's xp
        const uint4* h4 = (const uint4*)(hb + cur * 512);
        // LDS-resident pairs 0..63 (chunks of 8 pairs)
#pragma unroll
        for (int c = 0; c < 8; ++c) {
            uint4 ha = h4[2 * c], hc = h4[2 * c + 1];
            uint2 w0 = w2[(4 * c + 0) * 512 + j];
            uint2 w1 = w2[(4 * c + 1) * 512 + j];
            uint2 wv2 = w2[(4 * c + 2) * 512 + j];
            uint2 w3 = w2[(4 * c + 3) * 512 + j];
            acc = dot2f(ha.x, w0.x, acc);
            acc = dot2f(ha.y, w0.y, acc);
            acc = dot2f(ha.z, w1.x, acc);
            acc = dot2f(ha.w, w1.y, acc);
            acc = dot2f(hc.x, wv2.x, acc);
            acc = dot2f(hc.y, wv2.y, acc);
            acc = dot2f(hc.z, w3.x, acc);
            acc = dot2f(hc.w, w3.y, acc);
        }
        // register-resident pairs 64..255
#pragma unroll
        for (int c = 0; c < 24; ++c) {
            uint4 ha = h4[16 + 2 * c], hc = h4[17 + 2 * c];
            acc = dot2f(ha.x, wreg[8 * c + 0], acc);
            acc = dot2f(ha.y, wreg[8 * c + 1], acc);
            acc = dot2f(ha.z, wreg[8 * c + 2], acc);
            acc = dot2f(ha.w, wreg[8 * c + 3], acc);
            acc = dot2f(hc.x, wreg[8 * c + 4], acc);
            acc = dot2f(hc.y, wreg[8 * c + 5], acc);
            acc = dot2f(hc.z, wreg[8 * c + 6], acc);
            acc = dot2f(hc.w, wreg[8 * c + 7], acc);
        }
        hn = tanhf(acc);
        hb[(cur ^ 1) * 512 + j] = __float2half(hn);
        xpv = __half2float(nxt);
        __syncthreads();
        cur ^= 1;
    }

    // epilogue: out[b] = h_last . Wfc + bfc - 0.05
    float v = hn * Wfc[j];
#pragma unroll
    for (int off = 32; off; off >>= 1) v += __shfl_down(v, off, 64);
    float* red = (float*)hb;  // reuse LDS (all reads of hb are done)
    int lane = j & 63, wid = j >> 6;
    if (lane == 0) red[wid] = v;
    __syncthreads();
    if (j == 0) {
        float s = 0.f;
        for (int w = 0; w < 8; ++w) s += red[w];
        out[b] = s + bfc[0] - 0.05f;
    }
}

extern "C" void kernel_launch(void* const* d_in, const int* in_sizes, int n_in,
                              void* d_out, int out_size, void* d_ws, size_t ws_size,
                              hipStream_t stream) {
    const float* x   = (const float*)d_in[0];
    const float* Wx  = (const float*)d_in[1];
    const float* Wh  = (const float*)d_in[2];
    const float* b   = (const float*)d_in[3];
    const float* Wfc = (const float*)d_in[4];
    const float* bfc = (const float*)d_in[5];
    float* out = (float*)d_out;

    char* ws = (char*)d_ws;
    __half* xp = (__half*)ws;                               // 134,217,728 B
    u32* Wxpk  = (u32*)(ws + 134217728);                    //     262,144 B
    u32* Whpk  = (u32*)(ws + 134217728 + 262144);           //     524,288 B

    prepack_kernel<<<768, 256, 0, stream>>>(Wx, Wh, Wxpk, Whpk);
    xp_gemm_kernel<<<(B_ * T_) / 16, 512, 0, stream>>>(x, Wxpk, b, xp);

    const int dyn = 32 * 512 * 8 + 2048;  // 133120 B
    (void)hipFuncSetAttribute((const void*)rnn_kernel,
                              hipFuncAttributeMaxDynamicSharedMemorySize, dyn);
    rnn_kernel<<<B_, 512, dyn, stream>>>(xp, Whpk, Wfc, bfc, out);
}